// Round 9
// baseline (513.948 us; speedup 1.0000x reference)
//
#include <hip/hip_runtime.h>
#include <hip/hip_bf16.h>

#define BB 1024
#define DD 512
#define KK 1024
#define HH 32

typedef float f32x2 __attribute__((ext_vector_type(2)));
typedef float f32x4 __attribute__((ext_vector_type(4)));

// d_out (f32): [0,1048576) logits; [1048576,1049600) bmu_index; [1049600] delta
// ws: amin 1024xu64 @0 (8KB); partials 4096xf32 @8192 (16KB); rowstats @24576 (8KB)

__device__ __forceinline__ float dev_invtemp(int traw) {
    int t = traw;
    if (t > 100 || t < 0) t = (int)__int_as_float(traw);
    const float tf = (float)t;
    float temp;
    if (10.0f > tf)
        temp = 1e-8f + 0.5f * (10.0f - 1e-8f) * (1.0f + cosf(tf * 0.31415926535897932f));
    else
        temp = 1e-8f;
    return 1.0f / temp;
}

// ---- VOP3P packed f32 (gfx950: only pk_add/pk_mul/pk_fma exist for f32) ----
__device__ __forceinline__ f32x2 pk_sub(f32x2 a, f32x2 b) {   // {a.x-b.x, a.y-b.y}
    f32x2 r;
    asm("v_pk_add_f32 %0, %1, %2 neg_lo:[0,1] neg_hi:[0,1]" : "=v"(r) : "v"(a), "v"(b));
    return r;
}
__device__ __forceinline__ f32x2 pk_sq_acc(f32x2 d, f32x2 acc) {
    // acc + d*d with SEPARATE roundings (mul then add) — numpy-exact, NOT fma
    f32x2 m, r;
    asm("v_pk_mul_f32 %0, %1, %1" : "=v"(m) : "v"(d));
    asm("v_pk_add_f32 %0, %1, %2" : "=v"(r) : "v"(m), "v"(acc));
    return r;
}

// ---------------------------------------------------------------------------
// Kernel 1: per-row MLP; logits -> d_out (f32); softmax stats -> rowstats.
// ---------------------------------------------------------------------------
__global__ __launch_bounds__(256) void mlp_softmax_kernel(
    const float* __restrict__ X, const float* __restrict__ W1,
    const float* __restrict__ B1, const float* __restrict__ W2,
    const float* __restrict__ B2, const float* __restrict__ G,
    const int* __restrict__ T, float* __restrict__ out_logits,
    float2* __restrict__ rowstats, unsigned long long* __restrict__ amin)
{
    const int b = blockIdx.x;
    const int tid = threadIdx.x;
    __shared__ float xs[DD];
    __shared__ float hp[8][HH];
    __shared__ float hs[HH];
    __shared__ float red[256];

    if (tid < 128) ((float4*)xs)[tid] = ((const float4*)(X + (size_t)b * DD))[tid];
    if (tid == 0) amin[b] = ~0ULL;
    __syncthreads();

    {
        const int h = tid & 31, seg = tid >> 5;
        const float* w1p = W1 + (seg * 64) * HH + h;
        const float* xp = xs + seg * 64;
        float p = 0.f;
        #pragma unroll 8
        for (int d = 0; d < 64; ++d) p = fmaf(xp[d], w1p[d * HH], p);
        hp[seg][h] = p;
    }
    __syncthreads();
    if (tid < HH) {
        float a = ((hp[0][tid] + hp[1][tid]) + (hp[2][tid] + hp[3][tid]))
                + ((hp[4][tid] + hp[5][tid]) + (hp[6][tid] + hp[7][tid]));
        a += B1[tid];
        hs[tid] = a > 0.f ? a : 0.f;
    }
    const float invt = dev_invtemp(*T);
    __syncthreads();

    float sv[4];
    #pragma unroll
    for (int j = 0; j < 4; ++j) {
        const int k = tid + j * 256;
        float acc = B2[k];
        #pragma unroll
        for (int h = 0; h < HH; ++h) acc = fmaf(hs[h], W2[h * KK + k], acc);
        out_logits[(size_t)b * KK + k] = acc;
        sv[j] = (acc + G[(size_t)b * KK + k]) * invt;
    }

    float m = fmaxf(fmaxf(sv[0], sv[1]), fmaxf(sv[2], sv[3]));
    red[tid] = m;
    __syncthreads();
    for (int st = 128; st > 0; st >>= 1) {
        if (tid < st) red[tid] = fmaxf(red[tid], red[tid + st]);
        __syncthreads();
    }
    const float mx = red[0];
    __syncthreads();

    float psum = 0.f;
    #pragma unroll
    for (int j = 0; j < 4; ++j) psum += expf(sv[j] - mx);
    red[tid] = psum;
    __syncthreads();
    for (int st = 128; st > 0; st >>= 1) {
        if (tid < st) red[tid] += red[tid + st];
        __syncthreads();
    }
    if (tid == 0) rowstats[b] = make_float2(mx, 1.0f / red[0]);
}

// ---------------------------------------------------------------------------
// Kernel 2 v6: ONE output (b,k) per thread for occupancy. 16b x 16k tile,
// grid 64x64. launch_bounds(256,8) forces <=64 VGPR -> 8 waves/SIMD (2x TLP).
// C tile (16 rows x 64 d) double-buffered in LDS; X direct from global (L1/L2,
// 16-lane broadcast). np-exact pairwise preserved: packed accum a holds np
// accums {2a,2a+1}; fold == ((r0+r1)+(r2+r3))+((r4+r5)+(r6+r7)); fd=(B0+B1)+
// (B2+B3) via s01/s23. Epilogue: shfl butterflies (deterministic).
// ---------------------------------------------------------------------------
__global__ __launch_bounds__(256, 8) void dist_kernel(
    const float* __restrict__ X, const float* __restrict__ C,
    const float* __restrict__ L, const float* __restrict__ G,
    const float2* __restrict__ RS, const int* __restrict__ T,
    unsigned long long* __restrict__ amin, float* __restrict__ partials)
{
    #pragma clang fp contract(off)
    __shared__ float cs[2][16][68];
    __shared__ float redz[4];

    const int tid = threadIdx.x;
    const int tx = tid & 15, ty = tid >> 4;       // thread output: (b0+ty, k0+tx)
    const int k0 = blockIdx.x * 16, b0 = blockIdx.y * 16;
    const int crow = tid >> 4;                    // staging row (= ty)
    const int cq = (tid & 15) * 4;                // staging d-offset 0..60

    const float* cg = C + (size_t)(k0 + crow) * DD + cq;
    const float* xr = X + (size_t)(b0 + ty) * DD;

    const f32x2 zero2 = {0.f, 0.f};
    f32x2 rc[4] = {zero2, zero2, zero2, zero2};   // packed np accums {2a,2a+1}
    float s01 = 0.f, s23 = 0.f, l1 = 0.f;

    f32x4 cv = *(const f32x4*)cg;                 // chunk 0 C stage

    #pragma unroll 1
    for (int t = 0; t < 8; ++t) {                 // 8 chunks of 64 d
        const int buf = t & 1;
        *(f32x4*)&cs[buf][crow][cq] = cv;
        if (t < 7) cv = *(const f32x4*)(cg + (t + 1) * 64);  // reg-only: barrier-safe
        __syncthreads();

        const int d0 = t * 64;
        #pragma unroll
        for (int gp = 0; gp < 8; ++gp) {          // 8 d per gp
            const f32x4 xq0 = *(const f32x4*)(xr + d0 + 8 * gp);
            const f32x4 xq1 = *(const f32x4*)(xr + d0 + 8 * gp + 4);
            const f32x4 cq0 = *(const f32x4*)&cs[buf][tx][8 * gp];
            const f32x4 cq1 = *(const f32x4*)&cs[buf][tx][8 * gp + 4];
            f32x2 d;
            d = pk_sub(__builtin_shufflevector(cq0, cq0, 0, 1),
                       __builtin_shufflevector(xq0, xq0, 0, 1));
            rc[0] = pk_sq_acc(d, rc[0]); l1 += fabsf(d.x); l1 += fabsf(d.y);
            d = pk_sub(__builtin_shufflevector(cq0, cq0, 2, 3),
                       __builtin_shufflevector(xq0, xq0, 2, 3));
            rc[1] = pk_sq_acc(d, rc[1]); l1 += fabsf(d.x); l1 += fabsf(d.y);
            d = pk_sub(__builtin_shufflevector(cq1, cq1, 0, 1),
                       __builtin_shufflevector(xq1, xq1, 0, 1));
            rc[2] = pk_sq_acc(d, rc[2]); l1 += fabsf(d.x); l1 += fabsf(d.y);
            d = pk_sub(__builtin_shufflevector(cq1, cq1, 2, 3),
                       __builtin_shufflevector(xq1, xq1, 2, 3));
            rc[3] = pk_sq_acc(d, rc[3]); l1 += fabsf(d.x); l1 += fabsf(d.y);
        }

        if (t & 1) {                              // end of a 128-element block
            const int blk = t >> 1;               // 0..3
            // == ((r0+r1)+(r2+r3)) + ((r4+r5)+(r6+r7)) bit-exactly
            const float b01 = (rc[0].x + rc[0].y) + (rc[1].x + rc[1].y);
            const float b23 = (rc[2].x + rc[2].y) + (rc[3].x + rc[3].y);
            const float bsum = b01 + b23;
            if (blk == 0)      s01 = bsum;
            else if (blk == 1) s01 = s01 + bsum;
            else if (blk == 2) s23 = bsum;
            else               s23 = s23 + bsum;
            rc[0] = zero2; rc[1] = zero2; rc[2] = zero2; rc[3] = zero2;
        }
    }

    // ---- epilogue: z, delta partial (shfl butterfly), argmin (shfl) ----
    const float invt = dev_invtemp(*T);
    const int b = b0 + ty, k = k0 + tx;
    const float fd = s01 + s23;                   // ((B0+B1)+(B2+B3))
    const float2 rs = RS[b];
    const float z = expf((L[(size_t)b * KK + k] + G[(size_t)b * KK + k]) * invt - rs.x) * rs.y;
    float zp = l1 * z;

    // block delta partial: 64-lane butterfly + 4 wave values in fixed order
    #pragma unroll
    for (int w = 1; w < 64; w <<= 1) zp += __shfl_xor(zp, w, 64);
    if ((tid & 63) == 0) redz[tid >> 6] = zp;
    __syncthreads();
    if (tid == 0)
        partials[(size_t)blockIdx.y * 64 + blockIdx.x] =
            ((redz[0] + redz[1]) + (redz[2] + redz[3]));

    // per-row argmin over the 16 tx lanes (ties -> lowest k), then atomicMin
    unsigned long long p =
        ((unsigned long long)__float_as_uint(fd) << 32) | (unsigned long long)k;
    #pragma unroll
    for (int w = 1; w < 16; w <<= 1) {
        unsigned long long q = __shfl_xor(p, w, 64);
        p = q < p ? q : p;
    }
    if (tx == 0) atomicMin(&amin[b], p);
}

// ---------------------------------------------------------------------------
// Kernel 3: finalize — indices + deterministic sum of 4096 partials.
// ---------------------------------------------------------------------------
__global__ __launch_bounds__(1024) void finalize_kernel(
    const unsigned long long* __restrict__ amin,
    const float* __restrict__ partials, float* __restrict__ out)
{
    const int t = threadIdx.x;
    __shared__ float red[1024];
    const unsigned int idx = (unsigned int)(amin[t] & 0xFFFFFFFFULL);
    out[1048576 + t] = (float)idx;
    red[t] = ((partials[t] + partials[t + 1024]) + (partials[t + 2048] + partials[t + 3072]));
    __syncthreads();
    for (int st = 512; st > 0; st >>= 1) {
        if (t < st) red[t] += red[t + st];
        __syncthreads();
    }
    if (t == 0)
        out[1049600] = red[0] * (1.0f / 536870912.0f); // /(B*K*D)
}

extern "C" void kernel_launch(void* const* d_in, const int* in_sizes, int n_in,
                              void* d_out, int out_size, void* d_ws, size_t ws_size,
                              hipStream_t stream) {
    const float* X  = (const float*)d_in[0];
    const float* C  = (const float*)d_in[1];
    const float* W1 = (const float*)d_in[2];
    const float* B1 = (const float*)d_in[3];
    const float* W2 = (const float*)d_in[4];
    const float* B2 = (const float*)d_in[5];
    const float* G  = (const float*)d_in[6];
    const int*   T  = (const int*)d_in[7];
    float* out = (float*)d_out;

    char* ws = (char*)d_ws;
    unsigned long long* amin = (unsigned long long*)ws;          // 8 KB
    float* partials = (float*)(ws + 8192);                       // 16 KB (4096)
    float2* rowstats = (float2*)(ws + 24576);                    // 8 KB

    mlp_softmax_kernel<<<BB, 256, 0, stream>>>(X, W1, B1, W2, B2, G, T, out, rowstats, amin);
    dist_kernel<<<dim3(64, 64), 256, 0, stream>>>(X, C, out, G, rowstats, T, amin, partials);
    finalize_kernel<<<1, 1024, 0, stream>>>(amin, partials, out);
}